// Round 3
// baseline (781.797 us; speedup 1.0000x reference)
//
#include <hip/hip_runtime.h>
#include <hip/hip_fp16.h>

#define N_NODES 50000
#define N_EDGES 800000
#define IN_DIM  128
#define EDGE_DIM 16
#define HID     64
#define HID2    128
#define OUT_DIM 8
#define N_LAYERS 4
#define NBUCK   391        // ceil(50000/128) buckets of 128 dst nodes
#define CCHUNK  4096       // edges per coarse block
#define CBLOCKS 196        // ceil(800000/4096)

typedef _Float16 half8 __attribute__((ext_vector_type(8)));
typedef float floatx4 __attribute__((ext_vector_type(4)));

// wave-uniform broadcast of lane l's float via v_readlane (SGPR result,
// folds into v_fma as the 1 allowed scalar operand; avoids ds_bpermute)
static __device__ __forceinline__ float bcast(float v, int l) {
    return __uint_as_float(__builtin_amdgcn_readlane(__float_as_uint(v), l));
}

// ---------------------------------------------------------------------------
// Two-level counting sort by dst.
// Level 1 (coarse, 128-node buckets): LDS histogram -> contiguous per-block
// runs reserved with one global atomic per (block,bucket) -> line-friendly
// 8B-entry writes. Level 2: per-bucket LDS counting sort -> streaming writes.
// Entry packing: word0 = src | dst<<16 (both < 2^16), word1 = edge id.
// fsort additionally emits CSR row offsets roff[n] (per-dst-node edge start).
// ---------------------------------------------------------------------------
__global__ __launch_bounds__(256, 4) void chist_kernel(
    const int* __restrict__ dsts, int* __restrict__ ccnt)
{
    __shared__ int lh[NBUCK];
    for (int i = threadIdx.x; i < NBUCK; i += 256) lh[i] = 0;
    __syncthreads();
    const int base = blockIdx.x * CCHUNK;
#pragma unroll
    for (int i = 0; i < 16; ++i) {
        const int e = base + i * 256 + threadIdx.x;
        if (e < N_EDGES) atomicAdd(&lh[dsts[e] >> 7], 1);
    }
    __syncthreads();
    for (int i = threadIdx.x; i < NBUCK; i += 256)
        if (lh[i]) atomicAdd(&ccnt[i], lh[i]);
}

// single block: exclusive scan of 391 bucket counts -> coff[0..391], ccur copy
__global__ __launch_bounds__(256, 1) void cscan_kernel(
    const int* __restrict__ ccnt, int* __restrict__ coff, int* __restrict__ ccur)
{
    __shared__ int part[512];
    const int t = threadIdx.x;
    part[t]       = (t < NBUCK)       ? ccnt[t]       : 0;
    part[t + 256] = (t + 256 < NBUCK) ? ccnt[t + 256] : 0;
    __syncthreads();
    for (int off = 1; off < 512; off <<= 1) {
        const int v0 = (t >= off) ? part[t - off] : 0;
        const int v1 = (t + 256 >= off) ? part[t + 256 - off] : 0;
        __syncthreads();
        part[t] += v0; part[t + 256] += v1;
        __syncthreads();
    }
    if (t < NBUCK) { const int ex = (t > 0) ? part[t - 1] : 0; coff[t] = ex; ccur[t] = ex; }
    const int i2 = t + 256;
    if (i2 < NBUCK) { coff[i2] = part[i2 - 1]; ccur[i2] = part[i2 - 1]; }
    if (t == 0) coff[NBUCK] = part[NBUCK - 1];
}

__global__ __launch_bounds__(256, 4) void cscatter_kernel(
    const int* __restrict__ srcs, const int* __restrict__ dsts,
    int* __restrict__ ccur, uint2* __restrict__ tmp)
{
    __shared__ int lh[NBUCK], lbase[NBUCK], lrank[NBUCK];
    for (int i = threadIdx.x; i < NBUCK; i += 256) { lh[i] = 0; lrank[i] = 0; }
    __syncthreads();
    const int base = blockIdx.x * CCHUNK;
    int myd[16], mys[16];
#pragma unroll
    for (int i = 0; i < 16; ++i) {
        const int e = base + i * 256 + threadIdx.x;
        if (e < N_EDGES) {
            myd[i] = dsts[e]; mys[i] = srcs[e];
            atomicAdd(&lh[myd[i] >> 7], 1);
        } else myd[i] = -1;
    }
    __syncthreads();
    for (int i = threadIdx.x; i < NBUCK; i += 256) {
        const int c = lh[i];
        lbase[i] = c ? atomicAdd(&ccur[i], c) : 0;
    }
    __syncthreads();
#pragma unroll
    for (int i = 0; i < 16; ++i) {
        if (myd[i] >= 0) {
            const int e = base + i * 256 + threadIdx.x;
            const int b = myd[i] >> 7;
            const int r = atomicAdd(&lrank[b], 1);
            tmp[lbase[b] + r] =
                make_uint2((unsigned)mys[i] | ((unsigned)myd[i] << 16),
                           (unsigned)e);
        }
    }
}

// one block per bucket: LDS counting sort over the 128 local dsts.
// Also writes roff[b*128+d] = global start of node (b*128+d)'s edge run.
__global__ __launch_bounds__(256, 1) void fsort_kernel(
    const uint2* __restrict__ tmp, const int* __restrict__ coff,
    unsigned* __restrict__ sd2, int* __restrict__ eid,
    int* __restrict__ roff)
{
    __shared__ uint2 ebuf[4096];
    __shared__ int lh[128], lsc[128];
    const int b = blockIdx.x;
    const int lo = coff[b];
    const int cnt = coff[b + 1] - lo;
    if (threadIdx.x < 128) lh[threadIdx.x] = 0;
    __syncthreads();
    for (int i = threadIdx.x; i < cnt; i += 256) {
        const uint2 v = tmp[lo + i];
        ebuf[i] = v;
        atomicAdd(&lh[(int)(v.x >> 16) - b * 128], 1);
    }
    __syncthreads();
    if (threadIdx.x < 128) lsc[threadIdx.x] = lh[threadIdx.x];
    __syncthreads();
    for (int off = 1; off < 128; off <<= 1) {
        int v = 0;
        if (threadIdx.x < 128 && threadIdx.x >= off) v = lsc[threadIdx.x - off];
        __syncthreads();
        if (threadIdx.x < 128) lsc[threadIdx.x] += v;
        __syncthreads();
    }
    if (threadIdx.x < 128) {
        lh[threadIdx.x] = lsc[threadIdx.x] - lh[threadIdx.x];   // exclusive
        roff[b * 128 + threadIdx.x] = lo + lh[threadIdx.x];     // CSR start
        if (b == NBUCK - 1 && threadIdx.x == 127)
            roff[NBUCK * 128] = lo + cnt;                       // guard tail
    }
    __syncthreads();
    for (int i = threadIdx.x; i < cnt; i += 256) {
        const uint2 v = ebuf[i];
        const int d = (int)(v.x >> 16) - b * 128;
        const int pos = atomicAdd(&lh[d], 1);
        sd2[lo + pos] = v.x;
        eid[lo + pos] = (int)v.y;
    }
}

// ---------------------------------------------------------------------------
// h0 = x @ node_W + node_b      [N,128]@[128,64]; also fp16 copy for gathers
// ---------------------------------------------------------------------------
__global__ __launch_bounds__(256, 2) void node_proj_kernel(
    const float* __restrict__ x, const float* __restrict__ W,
    const float* __restrict__ b, float* __restrict__ h, __half* __restrict__ zh)
{
    __shared__ float xs[4][IN_DIM];
    const int c = threadIdx.x & 63;
    const int local_n = threadIdx.x >> 6;
    float w[IN_DIM];
#pragma unroll
    for (int k = 0; k < IN_DIM; ++k) w[k] = W[k * HID + c];
    const float bias = b[c];

    for (int base = blockIdx.x * 4; base < N_NODES; base += gridDim.x * 4) {
        __syncthreads();
#pragma unroll
        for (int i = 0; i < 2; ++i) {
            int idx = threadIdx.x + i * 256;
            int nn = idx >> 7, kk = idx & 127;
            xs[nn][kk] = x[(base + nn) * IN_DIM + kk];
        }
        __syncthreads();
        const int n = base + local_n;
        float acc = bias;
#pragma unroll
        for (int k4 = 0; k4 < IN_DIM / 4; ++k4) {
            float4 xv = ((const float4*)xs[local_n])[k4];
            acc = fmaf(xv.x, w[k4 * 4 + 0], acc);
            acc = fmaf(xv.y, w[k4 * 4 + 1], acc);
            acc = fmaf(xv.z, w[k4 * 4 + 2], acc);
            acc = fmaf(xv.w, w[k4 * 4 + 3], acc);
        }
        h[n * HID + c] = acc;
        zh[n * HID + c] = __float2half(acc);
    }
}

// ---------------------------------------------------------------------------
// edge embedding via MFMA (16 edges/wave, K padded 16->32), LDS transpose.
// Reads ea[eid[pos]] (random 64B full-line gathers), stores eah STREAMING.
// ---------------------------------------------------------------------------
__global__ __launch_bounds__(256, 4) void edge_emb_kernel(
    const float* __restrict__ ea, const float* __restrict__ W,
    const float* __restrict__ b, const int* __restrict__ eid,
    __half* __restrict__ eah)
{
    __shared__ __half lds_t[4][16 * HID];            // 2KB per wave
    const int lane = threadIdx.x & 63;
    const int waveid = threadIdx.x >> 6;
    const int wave = (blockIdx.x * 256 + threadIdx.x) >> 6;
    const int nwaves = gridDim.x * 4;
    const int m = lane & 15, q = lane >> 4;
    const int NT = N_EDGES / 16;                     // 50000

    half8 bf[4];
#pragma unroll
    for (int blk = 0; blk < 4; ++blk) {
#pragma unroll
        for (int i = 0; i < 8; ++i) {
            const int k = q * 8 + i;
            bf[blk][i] = (k < EDGE_DIM)
                ? (_Float16)W[k * HID + blk * 16 + m] : (_Float16)0.f;
        }
    }
    float bv[4];
#pragma unroll
    for (int blk = 0; blk < 4; ++blk) bv[blk] = b[blk * 16 + m];

    const int ed = lane >> 3, ch = lane & 7;         // store mapping

    for (int tile = wave; tile < NT; tile += nwaves) {
        const int e0 = tile * 16;
        const int eidx = eid[e0 + m];                // gather source row id
        half8 af;
#pragma unroll
        for (int i = 0; i < 8; ++i) af[i] = (_Float16)0.f;
        if (q < 2) {
            const float4* ap =
                (const float4*)(ea + (size_t)eidx * EDGE_DIM + q * 8);
            const float4 lo = ap[0];
            const float4 hi = ap[1];
            af[0] = (_Float16)lo.x; af[1] = (_Float16)lo.y;
            af[2] = (_Float16)lo.z; af[3] = (_Float16)lo.w;
            af[4] = (_Float16)hi.x; af[5] = (_Float16)hi.y;
            af[6] = (_Float16)hi.z; af[7] = (_Float16)hi.w;
        }
        floatx4 c[4];
#pragma unroll
        for (int blk = 0; blk < 4; ++blk) {
            floatx4 cin = {bv[blk], bv[blk], bv[blk], bv[blk]};
            c[blk] = __builtin_amdgcn_mfma_f32_16x16x32_f16(
                af, bf[blk], cin, 0, 0, 0);
        }
#pragma unroll
        for (int blk = 0; blk < 4; ++blk)
#pragma unroll
            for (int r = 0; r < 4; ++r)
                lds_t[waveid][(q * 4 + r) * HID + blk * 16 + m] =
                    __float2half(c[blk][r]);
        // streaming contiguous stores: 2x 16B per lane
        const float4 v0 =
            *(const float4*)&lds_t[waveid][ed * HID + ch * 8];
        const float4 v1 =
            *(const float4*)&lds_t[waveid][(8 + ed) * HID + ch * 8];
        ((float4*)(eah + (size_t)(e0 + ed) * HID))[ch] = v0;
        ((float4*)(eah + (size_t)(e0 + 8 + ed) * HID))[ch] = v1;
    }
}

// ---------------------------------------------------------------------------
// Node-major (CSR) segmented softmax-aggregate. One wave per dst node:
// eah rows contiguous (streaming), zh gathers 128B coalesced rows,
// S/P accumulate in registers -> NO atomics, NO ballots, NO boundary tests.
// Plain p/s stores (no pre-zero needed anywhere).
// ---------------------------------------------------------------------------
__global__ __launch_bounds__(256, 4) void edge_agg_kernel(
    const __half* __restrict__ zh, const __half* __restrict__ eah,
    const unsigned* __restrict__ sd2, const int* __restrict__ roff,
    const float* __restrict__ conv_t, int layer,
    float* __restrict__ p, float* __restrict__ s)
{
    const int lane = threadIdx.x & 63;
    const int wave = (blockIdx.x * 256 + threadIdx.x) >> 6;
    const int nwaves = gridDim.x * 4;
    const float t2 = conv_t[layer] * 1.4426950408889634f;  // log2(e)*t
    const float et2 = 1e-7f * t2;

    const _Float16* zf = (const _Float16*)zh;
    const _Float16* ef = (const _Float16*)eah;

    for (int n = wave; n < N_NODES; n += nwaves) {
        const int lo = roff[n];
        const int d = roff[n + 1] - lo;
        float S = 0.f, P = 0.f;

        for (int base = 0; base < d; base += 64) {     // deg>64 is ~impossible
            const int cnt = (d - base < 64) ? (d - base) : 64;
            const unsigned sdv = sd2[lo + base + (lane < cnt ? lane : cnt - 1)];
            const _Float16* ep = ef + (size_t)(lo + base) * HID + lane;

            _Float16 zr[4], er[4];
#pragma unroll
            for (int k = 0; k < 4; ++k) {
                if (k < cnt) {
                    const int a = (int)(__builtin_amdgcn_readlane(sdv, k) & 0xffffu);
                    zr[k] = zf[(size_t)a * HID + lane];
                    er[k] = ep[(size_t)k * HID];
                }
            }
            int i = 0;
            for (; i + 4 <= cnt; i += 4) {
#pragma unroll
                for (int k = 0; k < 4; ++k) {
                    _Float16 mh = zr[k] + er[k];
                    mh = mh > (_Float16)0.f ? mh : (_Float16)0.f;
                    const float mm = (float)mh;
                    const float xx = __builtin_amdgcn_exp2f(fmaf(mm, t2, et2));
                    S += xx;
                    P = fmaf(mm + 1e-7f, xx, P);
                    const int nx = i + 4 + k;          // prefetch distance 4
                    if (nx < cnt) {
                        const int a = (int)(__builtin_amdgcn_readlane(sdv, nx) & 0xffffu);
                        zr[k] = zf[(size_t)a * HID + lane];
                        er[k] = ep[(size_t)nx * HID];
                    }
                }
            }
#pragma unroll
            for (int k = 0; k < 4; ++k) {
                if (i + k < cnt) {
                    _Float16 mh = zr[k] + er[k];
                    mh = mh > (_Float16)0.f ? mh : (_Float16)0.f;
                    const float mm = (float)mh;
                    const float xx = __builtin_amdgcn_exp2f(fmaf(mm, t2, et2));
                    S += xx;
                    P = fmaf(mm + 1e-7f, xx, P);
                }
            }
        }
        p[(size_t)n * HID + lane] = P;                 // plain stores
        s[(size_t)n * HID + lane] = S;
    }
}

// ---------------------------------------------------------------------------
// mm1 v2: one node per WAVE, barrier-free.
// lane j computes outputs j and j+64 of u = hin@W1 + b1, hin = p/s + zh.
// LN over 128 via in-wave butterfly (each lane holds 2 of the 128 outputs).
// Weights register-resident (128 VGPR/lane); hin broadcast via v_readlane.
// ---------------------------------------------------------------------------
__global__ __launch_bounds__(256, 3) void node_mm1_kernel(
    const float* __restrict__ p, const float* __restrict__ s,
    const __half* __restrict__ zh,
    const float* __restrict__ W1, const float* __restrict__ b1,
    const float* __restrict__ g1, const float* __restrict__ be1,
    __half* __restrict__ vh)
{
    const int lane = threadIdx.x & 63;
    const int wave = (blockIdx.x * 256 + threadIdx.x) >> 6;
    const int nwaves = gridDim.x * 4;

    float wa[HID], wb[HID];
#pragma unroll
    for (int k = 0; k < HID; ++k) {
        wa[k] = W1[k * HID2 + lane];
        wb[k] = W1[k * HID2 + 64 + lane];
    }
    const float ba = b1[lane],  bb = b1[64 + lane];
    const float ga = g1[lane],  gb = g1[64 + lane];
    const float ca = be1[lane], cb = be1[64 + lane];

    for (int n = wave; n < N_NODES; n += nwaves) {
        const int idx = n * HID + lane;
        const float pv = p[idx];
        const float sv = s[idx];
        const float zv = __half2float(zh[idx]);
        const float hv = pv / (sv + 1e-16f) + zv;

        float a0 = 0.f, a1 = 0.f, c0 = 0.f, c1 = 0.f;  // 4 indep chains
#pragma unroll
        for (int k = 0; k < 32; ++k) {
            const float x0 = bcast(hv, k);
            const float x1 = bcast(hv, k + 32);
            a0 = fmaf(x0, wa[k], a0);
            c0 = fmaf(x0, wb[k], c0);
            a1 = fmaf(x1, wa[k + 32], a1);
            c1 = fmaf(x1, wb[k + 32], c1);
        }
        const float ua = (a0 + a1) + ba;
        const float ub = (c0 + c1) + bb;

        float sum = ua + ub;                         // LN over 128, in-wave
#pragma unroll
        for (int o = 1; o < 64; o <<= 1) sum += __shfl_xor(sum, o, 64);
        const float mu = sum * (1.f / 128.f);
        const float da = ua - mu, db = ub - mu;
        float q = fmaf(da, da, db * db);
#pragma unroll
        for (int o = 1; o < 64; o <<= 1) q += __shfl_xor(q, o, 64);
        const float rstd = rsqrtf(q * (1.f / 128.f) + 1e-5f);
        const float ya = da * rstd * ga + ca;
        const float yb = db * rstd * gb + cb;
        vh[(size_t)n * HID2 + lane]      = __float2half(ya > 0.f ? ya : 0.f);
        vh[(size_t)n * HID2 + 64 + lane] = __float2half(yb > 0.f ? yb : 0.f);
    }
}

// ---------------------------------------------------------------------------
// mm2 v2: one node per WAVE, barrier-free.
// lane c computes out2[c] = vh[n]@W2[:,c] + b2[c]; h = (res? h:0)+out2;
// zh = fp16(relu(LN64(h)*gz+bz)) with in-wave butterfly LN.
// ---------------------------------------------------------------------------
__global__ __launch_bounds__(256, 3) void node_mm2_kernel(
    const __half* __restrict__ vh,
    const float* __restrict__ W2, const float* __restrict__ b2,
    const float* __restrict__ lng, const float* __restrict__ lnb,
    float* __restrict__ h, __half* __restrict__ zh, int residual)
{
    const int lane = threadIdx.x & 63;
    const int wave = (blockIdx.x * 256 + threadIdx.x) >> 6;
    const int nwaves = gridDim.x * 4;

    float wa[HID2 / 2], wb[HID2 / 2];   // wa[k]=W2[k][c], wb[k]=W2[k+64][c]
#pragma unroll
    for (int k = 0; k < HID2 / 2; ++k) {
        wa[k] = W2[k * HID + lane];
        wb[k] = W2[(k + 64) * HID + lane];
    }
    const float bias = b2[lane];
    const float g = lng[lane];
    const float be = lnb[lane];

    for (int n = wave; n < N_NODES; n += nwaves) {
        const float f0 = __half2float(vh[(size_t)n * HID2 + lane]);
        const float f1 = __half2float(vh[(size_t)n * HID2 + 64 + lane]);

        float a0 = 0.f, a1 = 0.f, c0 = 0.f, c1 = 0.f;  // 4 indep chains
#pragma unroll
        for (int k = 0; k < 32; ++k) {
            const float x0 = bcast(f0, k);
            const float x1 = bcast(f0, k + 32);
            const float x2 = bcast(f1, k);
            const float x3 = bcast(f1, k + 32);
            a0 = fmaf(x0, wa[k], a0);
            a1 = fmaf(x1, wa[k + 32], a1);
            c0 = fmaf(x2, wb[k], c0);
            c1 = fmaf(x3, wb[k + 32], c1);
        }
        const float acc = (a0 + a1) + (c0 + c1) + bias;

        const int idx = n * HID + lane;
        const float hn = residual ? (h[idx] + acc) : acc;
        h[idx] = hn;

        float sum = hn;                               // LN over 64, in-wave
#pragma unroll
        for (int o = 1; o < 64; o <<= 1) sum += __shfl_xor(sum, o, 64);
        const float mu = sum * (1.f / 64.f);
        const float d = hn - mu;
        float q = d * d;
#pragma unroll
        for (int o = 1; o < 64; o <<= 1) q += __shfl_xor(q, o, 64);
        const float var = q * (1.f / 64.f);
        const float y = d * rsqrtf(var + 1e-5f) * g + be;
        zh[idx] = __float2half(y > 0.f ? y : 0.f);
    }
}

// ---------------------------------------------------------------------------
// out = zh @ lin_W + lin_b      [N,64]@[64,8]
// ---------------------------------------------------------------------------
__global__ __launch_bounds__(256, 4) void final_kernel(
    const __half* __restrict__ zh, const float* __restrict__ Wl,
    const float* __restrict__ bl, float* __restrict__ out)
{
    __shared__ float wl[HID * OUT_DIM];
    for (int i = threadIdx.x; i < HID * OUT_DIM; i += 256) wl[i] = Wl[i];
    __syncthreads();
    const int total = N_NODES * OUT_DIM;
    for (int idx = blockIdx.x * 256 + threadIdx.x; idx < total;
         idx += gridDim.x * 256) {
        const int n = idx >> 3, o = idx & 7;
        const __half2* zp = (const __half2*)(zh + (size_t)n * HID);
        float acc = bl[o];
#pragma unroll
        for (int k2 = 0; k2 < HID / 2; ++k2) {
            const float2 f = __half22float2(zp[k2]);
            acc = fmaf(f.x, wl[(k2 * 2 + 0) * OUT_DIM + o], acc);
            acc = fmaf(f.y, wl[(k2 * 2 + 1) * OUT_DIM + o], acc);
        }
        out[idx] = acc;
    }
}

// ---------------------------------------------------------------------------
extern "C" void kernel_launch(void* const* d_in, const int* in_sizes, int n_in,
                              void* d_out, int out_size, void* d_ws, size_t ws_size,
                              hipStream_t stream)
{
    const float* x         = (const float*)d_in[0];
    const float* edge_attr = (const float*)d_in[1];
    const float* node_W    = (const float*)d_in[2];
    const float* node_b    = (const float*)d_in[3];
    const float* edge_W    = (const float*)d_in[4];
    const float* edge_b    = (const float*)d_in[5];
    const float* conv_t    = (const float*)d_in[6];
    const float* conv_W1   = (const float*)d_in[7];
    const float* conv_b1   = (const float*)d_in[8];
    const float* conv_g1   = (const float*)d_in[9];
    const float* conv_be1  = (const float*)d_in[10];
    const float* conv_W2   = (const float*)d_in[11];
    const float* conv_b2   = (const float*)d_in[12];
    const float* ln_g      = (const float*)d_in[13];
    const float* ln_b      = (const float*)d_in[14];
    const float* lin_W     = (const float*)d_in[15];
    const float* lin_b     = (const float*)d_in[16];
    const int*   edge_index= (const int*)d_in[17];
    const int*   srcs = edge_index;
    const int*   dsts = edge_index + N_EDGES;
    float* out = (float*)d_out;

    // workspace layout (~173 MB)
    float* h   = (float*)d_ws;                    // N*64
    float* p   = h   + N_NODES * HID;             // N*64
    float* s   = p   + N_NODES * HID;             // N*64
    __half* vh  = (__half*)(s + N_NODES * HID);   // N*128 half
    __half* zh  = vh + (size_t)N_NODES * HID2;    // N*64 half
    __half* eah = zh + (size_t)N_NODES * HID;     // E*64 half
    uint2* tmp  = (uint2*)(eah + (size_t)N_EDGES * HID); // E x 8B
    unsigned* sd2 = (unsigned*)(tmp + N_EDGES);   // E x 4B
    int* eid    = (int*)(sd2 + N_EDGES);          // E x 4B
    int* roff   = eid + N_EDGES;                  // NBUCK*128+1 CSR offsets
    int* ccnt   = roff + NBUCK * 128 + 1;         // NBUCK
    int* coff   = ccnt + NBUCK;                   // NBUCK+1
    int* ccur   = coff + NBUCK + 1;               // NBUCK

    // ---- two-level counting sort of edges by dst (+ CSR roff) ----
    hipMemsetAsync(ccnt, 0, (size_t)NBUCK * sizeof(int), stream);
    chist_kernel<<<CBLOCKS, 256, 0, stream>>>(dsts, ccnt);
    cscan_kernel<<<1, 256, 0, stream>>>(ccnt, coff, ccur);
    cscatter_kernel<<<CBLOCKS, 256, 0, stream>>>(srcs, dsts, ccur, tmp);
    fsort_kernel<<<NBUCK, 256, 0, stream>>>(tmp, coff, sd2, eid, roff);

    node_proj_kernel<<<2048, 256, 0, stream>>>(x, node_W, node_b, h, zh);
    edge_emb_kernel<<<3125, 256, 0, stream>>>(edge_attr, edge_W, edge_b, eid, eah);

    for (int layer = 0; layer < N_LAYERS; ++layer) {
        edge_agg_kernel<<<6250, 256, 0, stream>>>(zh, eah, sd2, roff,
                                                  conv_t, layer, p, s);
        node_mm1_kernel<<<2048, 256, 0, stream>>>(
            p, s, zh,
            conv_W1 + (size_t)layer * HID * HID2, conv_b1 + layer * HID2,
            conv_g1 + layer * HID2, conv_be1 + layer * HID2, vh);
        const float* gz = (layer < N_LAYERS - 1) ? (ln_g + (layer + 1) * HID) : ln_g;
        const float* bz = (layer < N_LAYERS - 1) ? (ln_b + (layer + 1) * HID) : ln_b;
        node_mm2_kernel<<<2048, 256, 0, stream>>>(
            vh, conv_W2 + (size_t)layer * HID2 * HID, conv_b2 + layer * HID,
            gz, bz, h, zh, layer > 0 ? 1 : 0);
    }
    final_kernel<<<1024, 256, 0, stream>>>(zh, lin_W, lin_b, out);
}

// Round 5
// 768.952 us; speedup vs baseline: 1.0167x; 1.0167x over previous
//
#include <hip/hip_runtime.h>
#include <hip/hip_fp16.h>

#define N_NODES 50000
#define N_EDGES 800000
#define IN_DIM  128
#define EDGE_DIM 16
#define HID     64
#define HID2    128
#define OUT_DIM 8
#define N_LAYERS 4
#define NBUCK   391        // ceil(50000/128) buckets of 128 dst nodes
#define CCHUNK  4096       // edges per coarse block
#define CBLOCKS 196        // ceil(800000/4096)

typedef _Float16 half8 __attribute__((ext_vector_type(8)));
typedef float floatx4 __attribute__((ext_vector_type(4)));

// wave-uniform broadcast of lane l's float via v_readlane (SGPR result,
// folds into v_fma as the 1 allowed scalar operand; avoids ds_bpermute)
static __device__ __forceinline__ float bcast(float v, int l) {
    return __uint_as_float(__builtin_amdgcn_readlane(__float_as_uint(v), l));
}

// ---------------------------------------------------------------------------
// Two-level counting sort by dst.
// Entry packing: word0 = src | dst<<16 (both < 2^16), word1 = edge id.
// ---------------------------------------------------------------------------
__global__ __launch_bounds__(256, 4) void chist_kernel(
    const int* __restrict__ dsts, int* __restrict__ ccnt)
{
    __shared__ int lh[NBUCK];
    for (int i = threadIdx.x; i < NBUCK; i += 256) lh[i] = 0;
    __syncthreads();
    const int base = blockIdx.x * CCHUNK;
#pragma unroll
    for (int i = 0; i < 16; ++i) {
        const int e = base + i * 256 + threadIdx.x;
        if (e < N_EDGES) atomicAdd(&lh[dsts[e] >> 7], 1);
    }
    __syncthreads();
    for (int i = threadIdx.x; i < NBUCK; i += 256)
        if (lh[i]) atomicAdd(&ccnt[i], lh[i]);
}

// single block: exclusive scan of 391 bucket counts -> coff[0..391], ccur copy
__global__ __launch_bounds__(256, 1) void cscan_kernel(
    const int* __restrict__ ccnt, int* __restrict__ coff, int* __restrict__ ccur)
{
    __shared__ int part[512];
    const int t = threadIdx.x;
    part[t]       = (t < NBUCK)       ? ccnt[t]       : 0;
    part[t + 256] = (t + 256 < NBUCK) ? ccnt[t + 256] : 0;
    __syncthreads();
    for (int off = 1; off < 512; off <<= 1) {
        const int v0 = (t >= off) ? part[t - off] : 0;
        const int v1 = (t + 256 >= off) ? part[t + 256 - off] : 0;
        __syncthreads();
        part[t] += v0; part[t + 256] += v1;
        __syncthreads();
    }
    if (t < NBUCK) { const int ex = (t > 0) ? part[t - 1] : 0; coff[t] = ex; ccur[t] = ex; }
    const int i2 = t + 256;
    if (i2 < NBUCK) { coff[i2] = part[i2 - 1]; ccur[i2] = part[i2 - 1]; }
    if (t == 0) coff[NBUCK] = part[NBUCK - 1];
}

__global__ __launch_bounds__(256, 4) void cscatter_kernel(
    const int* __restrict__ srcs, const int* __restrict__ dsts,
    int* __restrict__ ccur, uint2* __restrict__ tmp)
{
    __shared__ int lh[NBUCK], lbase[NBUCK], lrank[NBUCK];
    for (int i = threadIdx.x; i < NBUCK; i += 256) { lh[i] = 0; lrank[i] = 0; }
    __syncthreads();
    const int base = blockIdx.x * CCHUNK;
    int myd[16], mys[16];
#pragma unroll
    for (int i = 0; i < 16; ++i) {
        const int e = base + i * 256 + threadIdx.x;
        if (e < N_EDGES) {
            myd[i] = dsts[e]; mys[i] = srcs[e];
            atomicAdd(&lh[myd[i] >> 7], 1);
        } else myd[i] = -1;
    }
    __syncthreads();
    for (int i = threadIdx.x; i < NBUCK; i += 256) {
        const int c = lh[i];
        lbase[i] = c ? atomicAdd(&ccur[i], c) : 0;
    }
    __syncthreads();
#pragma unroll
    for (int i = 0; i < 16; ++i) {
        if (myd[i] >= 0) {
            const int e = base + i * 256 + threadIdx.x;
            const int b = myd[i] >> 7;
            const int r = atomicAdd(&lrank[b], 1);
            tmp[lbase[b] + r] =
                make_uint2((unsigned)mys[i] | ((unsigned)myd[i] << 16),
                           (unsigned)e);
        }
    }
}

// one block per bucket: LDS counting sort over the 128 local dsts
__global__ __launch_bounds__(256, 1) void fsort_kernel(
    const uint2* __restrict__ tmp, const int* __restrict__ coff,
    unsigned* __restrict__ sd2, int* __restrict__ eid)
{
    __shared__ uint2 ebuf[4096];
    __shared__ int lh[128], lsc[128];
    const int b = blockIdx.x;
    const int lo = coff[b];
    const int cnt = coff[b + 1] - lo;
    if (threadIdx.x < 128) lh[threadIdx.x] = 0;
    __syncthreads();
    for (int i = threadIdx.x; i < cnt; i += 256) {
        const uint2 v = tmp[lo + i];
        ebuf[i] = v;
        atomicAdd(&lh[(int)(v.x >> 16) - b * 128], 1);
    }
    __syncthreads();
    if (threadIdx.x < 128) lsc[threadIdx.x] = lh[threadIdx.x];
    __syncthreads();
    for (int off = 1; off < 128; off <<= 1) {
        int v = 0;
        if (threadIdx.x < 128 && threadIdx.x >= off) v = lsc[threadIdx.x - off];
        __syncthreads();
        if (threadIdx.x < 128) lsc[threadIdx.x] += v;
        __syncthreads();
    }
    if (threadIdx.x < 128) lh[threadIdx.x] = lsc[threadIdx.x] - lh[threadIdx.x];
    __syncthreads();
    for (int i = threadIdx.x; i < cnt; i += 256) {
        const uint2 v = ebuf[i];
        const int d = (int)(v.x >> 16) - b * 128;
        const int pos = atomicAdd(&lh[d], 1);
        sd2[lo + pos] = v.x;
        eid[lo + pos] = (int)v.y;
    }
}

// ---------------------------------------------------------------------------
// h0 = x @ node_W + node_b      [N,128]@[128,64]; also fp16 copy for gathers
// ---------------------------------------------------------------------------
__global__ __launch_bounds__(256, 2) void node_proj_kernel(
    const float* __restrict__ x, const float* __restrict__ W,
    const float* __restrict__ b, float* __restrict__ h, __half* __restrict__ zh)
{
    __shared__ float xs[4][IN_DIM];
    const int c = threadIdx.x & 63;
    const int local_n = threadIdx.x >> 6;
    float w[IN_DIM];
#pragma unroll
    for (int k = 0; k < IN_DIM; ++k) w[k] = W[k * HID + c];
    const float bias = b[c];

    for (int base = blockIdx.x * 4; base < N_NODES; base += gridDim.x * 4) {
        __syncthreads();
#pragma unroll
        for (int i = 0; i < 2; ++i) {
            int idx = threadIdx.x + i * 256;
            int nn = idx >> 7, kk = idx & 127;
            xs[nn][kk] = x[(base + nn) * IN_DIM + kk];
        }
        __syncthreads();
        const int n = base + local_n;
        float acc = bias;
#pragma unroll
        for (int k4 = 0; k4 < IN_DIM / 4; ++k4) {
            float4 xv = ((const float4*)xs[local_n])[k4];
            acc = fmaf(xv.x, w[k4 * 4 + 0], acc);
            acc = fmaf(xv.y, w[k4 * 4 + 1], acc);
            acc = fmaf(xv.z, w[k4 * 4 + 2], acc);
            acc = fmaf(xv.w, w[k4 * 4 + 3], acc);
        }
        h[n * HID + c] = acc;
        zh[n * HID + c] = __float2half(acc);
    }
}

// ---------------------------------------------------------------------------
// edge embedding via MFMA (16 edges/wave, K padded 16->32), LDS transpose.
// Reads ea[eid[pos]] (random 64B full-line gathers), stores eah STREAMING.
// ---------------------------------------------------------------------------
__global__ __launch_bounds__(256, 4) void edge_emb_kernel(
    const float* __restrict__ ea, const float* __restrict__ W,
    const float* __restrict__ b, const int* __restrict__ eid,
    __half* __restrict__ eah)
{
    __shared__ __half lds_t[4][16 * HID];            // 2KB per wave
    const int lane = threadIdx.x & 63;
    const int waveid = threadIdx.x >> 6;
    const int wave = (blockIdx.x * 256 + threadIdx.x) >> 6;
    const int nwaves = gridDim.x * 4;
    const int m = lane & 15, q = lane >> 4;
    const int NT = N_EDGES / 16;                     // 50000

    half8 bf[4];
#pragma unroll
    for (int blk = 0; blk < 4; ++blk) {
#pragma unroll
        for (int i = 0; i < 8; ++i) {
            const int k = q * 8 + i;
            bf[blk][i] = (k < EDGE_DIM)
                ? (_Float16)W[k * HID + blk * 16 + m] : (_Float16)0.f;
        }
    }
    float bv[4];
#pragma unroll
    for (int blk = 0; blk < 4; ++blk) bv[blk] = b[blk * 16 + m];

    const int ed = lane >> 3, ch = lane & 7;         // store mapping

    for (int tile = wave; tile < NT; tile += nwaves) {
        const int e0 = tile * 16;
        const int eidx = eid[e0 + m];                // gather source row id
        half8 af;
#pragma unroll
        for (int i = 0; i < 8; ++i) af[i] = (_Float16)0.f;
        if (q < 2) {
            const float4* ap =
                (const float4*)(ea + (size_t)eidx * EDGE_DIM + q * 8);
            const float4 lo = ap[0];
            const float4 hi = ap[1];
            af[0] = (_Float16)lo.x; af[1] = (_Float16)lo.y;
            af[2] = (_Float16)lo.z; af[3] = (_Float16)lo.w;
            af[4] = (_Float16)hi.x; af[5] = (_Float16)hi.y;
            af[6] = (_Float16)hi.z; af[7] = (_Float16)hi.w;
        }
        floatx4 c[4];
#pragma unroll
        for (int blk = 0; blk < 4; ++blk) {
            floatx4 cin = {bv[blk], bv[blk], bv[blk], bv[blk]};
            c[blk] = __builtin_amdgcn_mfma_f32_16x16x32_f16(
                af, bf[blk], cin, 0, 0, 0);
        }
#pragma unroll
        for (int blk = 0; blk < 4; ++blk)
#pragma unroll
            for (int r = 0; r < 4; ++r)
                lds_t[waveid][(q * 4 + r) * HID + blk * 16 + m] =
                    __float2half(c[blk][r]);
        // streaming contiguous stores: 2x 16B per lane
        const float4 v0 =
            *(const float4*)&lds_t[waveid][ed * HID + ch * 8];
        const float4 v1 =
            *(const float4*)&lds_t[waveid][(8 + ed) * HID + ch * 8];
        ((float4*)(eah + (size_t)(e0 + ed) * HID))[ch] = v0;
        ((float4*)(eah + (size_t)(e0 + 8 + ed) * HID))[ch] = v1;
    }
}

// ---------------------------------------------------------------------------
// Edge-major segmented softmax-aggregate (round-1 structure, deeper MLP):
// ALL 64 eah streaming loads issued up-front (independent of sd2), zh
// gathers in 16-edge groups with depth-2 prefetch -> ~90 loads in flight.
// ---------------------------------------------------------------------------
__global__ __launch_bounds__(256, 3) void edge_agg_kernel(
    const __half* __restrict__ zh, const __half* __restrict__ eah,
    const unsigned* __restrict__ sd2,
    const float* __restrict__ conv_t, int layer,
    float* __restrict__ p, float* __restrict__ s)
{
    const int lane = threadIdx.x & 63;
    const int wave = (blockIdx.x * 256 + threadIdx.x) >> 6;
    const int nwaves = gridDim.x * 4;
    const float t2 = conv_t[layer] * 1.4426950408889634f;  // log2(e)*t
    const int NT = N_EDGES / 64;                     // 12500

    const _Float16* zf = (const _Float16*)zh;
    const _Float16* ef = (const _Float16*)eah;

    for (int tile = wave; tile < NT; tile += nwaves) {
        const int e0 = tile * 64;
        const unsigned sdv = sd2[e0 + lane];         // one coalesced 4B load
        const _Float16* erow = ef + (size_t)e0 * HID + lane;

        // issue ALL eah streaming loads up-front (no sd2 dependence)
        _Float16 ez[64];
#pragma unroll
        for (int k = 0; k < 64; ++k) ez[k] = erow[(size_t)k * HID];

        const int sv = (int)(sdv & 0xffffu);
        const int dv = (int)(sdv >> 16);
        const int pv = __shfl_up(dv, 1, 64);
        const unsigned long long bmask = __ballot(dv != pv) & ~1ull;

        _Float16 za[16], zb[16];
#pragma unroll
        for (int k = 0; k < 16; ++k) {               // prologue: group 0
            const int a = __builtin_amdgcn_readlane(sv, k);
            za[k] = zf[(size_t)a * HID + lane];
        }

        float S = 0.f, P = 0.f;
        int cur = __builtin_amdgcn_readlane(dv, 0);
#pragma unroll
        for (int g = 0; g < 4; ++g) {
            if (g < 3) {                             // prefetch group g+1
#pragma unroll
                for (int k = 0; k < 16; ++k) {
                    const int a = __builtin_amdgcn_readlane(sv, (g + 1) * 16 + k);
                    zb[k] = zf[(size_t)a * HID + lane];
                }
            }
#pragma unroll
            for (int k = 0; k < 16; ++k) {
                const int j = g * 16 + k;
                if (bmask & (1ull << j)) {           // SALU test, uniform
                    unsafeAtomicAdd(&s[(size_t)cur * HID + lane], S);
                    unsafeAtomicAdd(&p[(size_t)cur * HID + lane], P);
                    S = 0.f; P = 0.f;
                    cur = __builtin_amdgcn_readlane(dv, j);
                }
                _Float16 mh = za[k] + ez[j];
                mh = mh > (_Float16)0.f ? mh : (_Float16)0.f;
                const float mm = (float)mh + 1e-7f;
                const float xx = __builtin_amdgcn_exp2f(mm * t2);
                S += xx;
                P = fmaf(mm, xx, P);
            }
            if (g < 3) {
#pragma unroll
                for (int k = 0; k < 16; ++k) za[k] = zb[k];
            }
        }
        unsafeAtomicAdd(&s[(size_t)cur * HID + lane], S);
        unsafeAtomicAdd(&p[(size_t)cur * HID + lane], P);
    }
}

// ---------------------------------------------------------------------------
// FUSED node MLP: mm1 + LN128 + relu + mm2 + residual + LN64 + relu -> zh.
// 2 waves per node: wave w computes mm1 outputs j = w*64+lane (weights
// register-resident, 64 VGPR), LN128 two-pass via butterfly + 2-float LDS
// exchange, mm2 half-k-sum per wave using its OWN v via readlane (no LDS
// for v), halves combined through LDS. vh buffer eliminated entirely.
// Re-zeroes p,s for the next layer (after the stats barrier = after reads).
// ---------------------------------------------------------------------------
__global__ __launch_bounds__(256, 3) void node_mlp_kernel(
    float* __restrict__ p, float* __restrict__ s,
    const float* __restrict__ W1, const float* __restrict__ b1,
    const float* __restrict__ g1, const float* __restrict__ be1,
    const float* __restrict__ W2, const float* __restrict__ b2,
    const float* __restrict__ lng, const float* __restrict__ lnb,
    float* __restrict__ h, __half* zh, int residual)
{
    __shared__ float part1[2][HID];      // wave1's mm2 partial per node
    __shared__ float red[2][2][2];       // [node][phase][wave]
    const int lane = threadIdx.x & 63;
    const int waveid = threadIdx.x >> 6; // 0..3
    const int nodesel = waveid >> 1;     // which of the 2 nodes
    const int w = waveid & 1;            // output-half selector
    const int j = w * HID + lane;        // mm1 output index 0..127

    float w1c[HID], w2c[HID];
#pragma unroll
    for (int k = 0; k < HID; ++k) w1c[k] = W1[k * HID2 + j];
#pragma unroll
    for (int k = 0; k < HID; ++k) w2c[k] = W2[(w * HID + k) * HID + lane];
    const float b1j = b1[j], g1j = g1[j], be1j = be1[j];
    const float b2c = b2[lane], gz = lng[lane], bz = lnb[lane];

    for (int base = blockIdx.x * 2; base < N_NODES; base += gridDim.x * 2) {
        const int n = base + nodesel;
        const int idx = n * HID + lane;
        const float pv = p[idx];
        const float sv = s[idx];
        const float hv = pv / (sv + 1e-16f) + __half2float(zh[idx]);

        float a0 = 0.f, a1 = 0.f;
#pragma unroll
        for (int k = 0; k < 32; ++k) {
            a0 = fmaf(bcast(hv, k),      w1c[k],      a0);
            a1 = fmaf(bcast(hv, k + 32), w1c[k + 32], a1);
        }
        const float u = (a0 + a1) + b1j;

        float su = u;                    // LN128 pass 1: mean
#pragma unroll
        for (int o = 1; o < 64; o <<= 1) su += __shfl_xor(su, o, 64);
        if (lane == 0) red[nodesel][0][w] = su;
        __syncthreads();
        const float mu = (red[nodesel][0][0] + red[nodesel][0][1]) * (1.f / 128.f);
        if (w == 0) { p[idx] = 0.f; s[idx] = 0.f; }   // after all p/s reads

        const float d = u - mu;          // LN128 pass 2: variance
        float qd = d * d;
#pragma unroll
        for (int o = 1; o < 64; o <<= 1) qd += __shfl_xor(qd, o, 64);
        if (lane == 0) red[nodesel][1][w] = qd;
        __syncthreads();
        const float var = (red[nodesel][1][0] + red[nodesel][1][1]) * (1.f / 128.f);
        const float y = d * rsqrtf(var + 1e-5f) * g1j + be1j;
        const float v = y > 0.f ? y : 0.f;

        float q0 = 0.f, q1 = 0.f;        // mm2 half-k-sum with own v
#pragma unroll
        for (int k = 0; k < 32; ++k) {
            q0 = fmaf(bcast(v, k),      w2c[k],      q0);
            q1 = fmaf(bcast(v, k + 32), w2c[k + 32], q1);
        }
        const float partial = q0 + q1;
        if (w == 1) part1[nodesel][lane] = partial;
        __syncthreads();
        if (w == 0) {
            const float acc = partial + part1[nodesel][lane] + b2c;
            const float hn = residual ? (h[idx] + acc) : acc;
            h[idx] = hn;
            float s2 = hn;               // LN64 two-pass, in-wave
#pragma unroll
            for (int o = 1; o < 64; o <<= 1) s2 += __shfl_xor(s2, o, 64);
            const float mu2 = s2 * (1.f / 64.f);
            const float d2 = hn - mu2;
            float q2 = d2 * d2;
#pragma unroll
            for (int o = 1; o < 64; o <<= 1) q2 += __shfl_xor(q2, o, 64);
            const float var2 = q2 * (1.f / 64.f);
            const float yy = d2 * rsqrtf(var2 + 1e-5f) * gz + bz;
            zh[idx] = __float2half(yy > 0.f ? yy : 0.f);
        }
    }
}

// ---------------------------------------------------------------------------
// out = zh @ lin_W + lin_b      [N,64]@[64,8]
// ---------------------------------------------------------------------------
__global__ __launch_bounds__(256, 4) void final_kernel(
    const __half* __restrict__ zh, const float* __restrict__ Wl,
    const float* __restrict__ bl, float* __restrict__ out)
{
    __shared__ float wl[HID * OUT_DIM];
    for (int i = threadIdx.x; i < HID * OUT_DIM; i += 256) wl[i] = Wl[i];
    __syncthreads();
    const int total = N_NODES * OUT_DIM;
    for (int idx = blockIdx.x * 256 + threadIdx.x; idx < total;
         idx += gridDim.x * 256) {
        const int n = idx >> 3, o = idx & 7;
        const __half2* zp = (const __half2*)(zh + (size_t)n * HID);
        float acc = bl[o];
#pragma unroll
        for (int k2 = 0; k2 < HID / 2; ++k2) {
            const float2 f = __half22float2(zp[k2]);
            acc = fmaf(f.x, wl[(k2 * 2 + 0) * OUT_DIM + o], acc);
            acc = fmaf(f.y, wl[(k2 * 2 + 1) * OUT_DIM + o], acc);
        }
        out[idx] = acc;
    }
}

// ---------------------------------------------------------------------------
extern "C" void kernel_launch(void* const* d_in, const int* in_sizes, int n_in,
                              void* d_out, int out_size, void* d_ws, size_t ws_size,
                              hipStream_t stream)
{
    const float* x         = (const float*)d_in[0];
    const float* edge_attr = (const float*)d_in[1];
    const float* node_W    = (const float*)d_in[2];
    const float* node_b    = (const float*)d_in[3];
    const float* edge_W    = (const float*)d_in[4];
    const float* edge_b    = (const float*)d_in[5];
    const float* conv_t    = (const float*)d_in[6];
    const float* conv_W1   = (const float*)d_in[7];
    const float* conv_b1   = (const float*)d_in[8];
    const float* conv_g1   = (const float*)d_in[9];
    const float* conv_be1  = (const float*)d_in[10];
    const float* conv_W2   = (const float*)d_in[11];
    const float* conv_b2   = (const float*)d_in[12];
    const float* ln_g      = (const float*)d_in[13];
    const float* ln_b      = (const float*)d_in[14];
    const float* lin_W     = (const float*)d_in[15];
    const float* lin_b     = (const float*)d_in[16];
    const int*   edge_index= (const int*)d_in[17];
    const int*   srcs = edge_index;
    const int*   dsts = edge_index + N_EDGES;
    float* out = (float*)d_out;

    // workspace layout (~160 MB)
    float* h   = (float*)d_ws;                    // N*64
    float* p   = h   + N_NODES * HID;             // N*64
    float* s   = p   + N_NODES * HID;             // N*64 (contiguous w/ p)
    __half* zh  = (__half*)(s + N_NODES * HID);   // N*64 half
    __half* eah = zh + (size_t)N_NODES * HID;     // E*64 half
    uint2* tmp  = (uint2*)(eah + (size_t)N_EDGES * HID); // E x 8B
    unsigned* sd2 = (unsigned*)(tmp + N_EDGES);   // E x 4B
    int* eid    = (int*)(sd2 + N_EDGES);          // E x 4B
    int* ccnt   = eid + N_EDGES;                  // NBUCK
    int* coff   = ccnt + NBUCK;                   // NBUCK+1
    int* ccur   = coff + NBUCK + 1;               // NBUCK

    // ---- two-level counting sort of edges by dst ----
    hipMemsetAsync(ccnt, 0, (size_t)NBUCK * sizeof(int), stream);
    chist_kernel<<<CBLOCKS, 256, 0, stream>>>(dsts, ccnt);
    cscan_kernel<<<1, 256, 0, stream>>>(ccnt, coff, ccur);
    cscatter_kernel<<<CBLOCKS, 256, 0, stream>>>(srcs, dsts, ccur, tmp);
    fsort_kernel<<<NBUCK, 256, 0, stream>>>(tmp, coff, sd2, eid);

    node_proj_kernel<<<2048, 256, 0, stream>>>(x, node_W, node_b, h, zh);
    edge_emb_kernel<<<3125, 256, 0, stream>>>(edge_attr, edge_W, edge_b, eid, eah);

    // zero p,s once; node_mlp re-zeroes them for the next layer
    hipMemsetAsync(p, 0, (size_t)2 * N_NODES * HID * sizeof(float), stream);

    for (int layer = 0; layer < N_LAYERS; ++layer) {
        edge_agg_kernel<<<3125, 256, 0, stream>>>(zh, eah, sd2,
                                                  conv_t, layer, p, s);
        const float* gz = (layer < N_LAYERS - 1) ? (ln_g + (layer + 1) * HID) : ln_g;
        const float* bz = (layer < N_LAYERS - 1) ? (ln_b + (layer + 1) * HID) : ln_b;
        node_mlp_kernel<<<2048, 256, 0, stream>>>(
            p, s,
            conv_W1 + (size_t)layer * HID * HID2, conv_b1 + layer * HID2,
            conv_g1 + layer * HID2, conv_be1 + layer * HID2,
            conv_W2 + (size_t)layer * HID2 * HID, conv_b2 + layer * HID,
            gz, bz, h, zh, layer > 0 ? 1 : 0);
    }
    final_kernel<<<1024, 256, 0, stream>>>(zh, lin_W, lin_b, out);
}

// Round 6
// 673.899 us; speedup vs baseline: 1.1601x; 1.1410x over previous
//
#include <hip/hip_runtime.h>
#include <hip/hip_fp16.h>

#define N_NODES 50000
#define N_EDGES 800000
#define IN_DIM  128
#define EDGE_DIM 16
#define HID     64
#define HID2    128
#define OUT_DIM 8
#define N_LAYERS 4
#define NBUCK   391        // ceil(50000/128) buckets of 128 dst nodes
#define CCHUNK  4096       // edges per coarse block
#define CBLOCKS 196        // ceil(800000/4096)

typedef _Float16 half8 __attribute__((ext_vector_type(8)));
typedef float floatx4 __attribute__((ext_vector_type(4)));

// wave-uniform broadcast of lane l's float via v_readlane (SGPR result,
// folds into v_fma as the 1 allowed scalar operand; avoids ds_bpermute)
static __device__ __forceinline__ float bcast(float v, int l) {
    return __uint_as_float(__builtin_amdgcn_readlane(__float_as_uint(v), l));
}

// ---------------------------------------------------------------------------
// Two-level counting sort by dst.
// Entry packing: word0 = src | dst<<16 (both < 2^16), word1 = edge id.
// ---------------------------------------------------------------------------
__global__ __launch_bounds__(256, 4) void chist_kernel(
    const int* __restrict__ dsts, int* __restrict__ ccnt)
{
    __shared__ int lh[NBUCK];
    for (int i = threadIdx.x; i < NBUCK; i += 256) lh[i] = 0;
    __syncthreads();
    const int base = blockIdx.x * CCHUNK;
#pragma unroll
    for (int i = 0; i < 16; ++i) {
        const int e = base + i * 256 + threadIdx.x;
        if (e < N_EDGES) atomicAdd(&lh[dsts[e] >> 7], 1);
    }
    __syncthreads();
    for (int i = threadIdx.x; i < NBUCK; i += 256)
        if (lh[i]) atomicAdd(&ccnt[i], lh[i]);
}

// single block: exclusive scan of 391 bucket counts -> coff[0..391], ccur copy
__global__ __launch_bounds__(256, 1) void cscan_kernel(
    const int* __restrict__ ccnt, int* __restrict__ coff, int* __restrict__ ccur)
{
    __shared__ int part[512];
    const int t = threadIdx.x;
    part[t]       = (t < NBUCK)       ? ccnt[t]       : 0;
    part[t + 256] = (t + 256 < NBUCK) ? ccnt[t + 256] : 0;
    __syncthreads();
    for (int off = 1; off < 512; off <<= 1) {
        const int v0 = (t >= off) ? part[t - off] : 0;
        const int v1 = (t + 256 >= off) ? part[t + 256 - off] : 0;
        __syncthreads();
        part[t] += v0; part[t + 256] += v1;
        __syncthreads();
    }
    if (t < NBUCK) { const int ex = (t > 0) ? part[t - 1] : 0; coff[t] = ex; ccur[t] = ex; }
    const int i2 = t + 256;
    if (i2 < NBUCK) { coff[i2] = part[i2 - 1]; ccur[i2] = part[i2 - 1]; }
    if (t == 0) coff[NBUCK] = part[NBUCK - 1];
}

__global__ __launch_bounds__(256, 4) void cscatter_kernel(
    const int* __restrict__ srcs, const int* __restrict__ dsts,
    int* __restrict__ ccur, uint2* __restrict__ tmp)
{
    __shared__ int lh[NBUCK], lbase[NBUCK], lrank[NBUCK];
    for (int i = threadIdx.x; i < NBUCK; i += 256) { lh[i] = 0; lrank[i] = 0; }
    __syncthreads();
    const int base = blockIdx.x * CCHUNK;
    int myd[16], mys[16];
#pragma unroll
    for (int i = 0; i < 16; ++i) {
        const int e = base + i * 256 + threadIdx.x;
        if (e < N_EDGES) {
            myd[i] = dsts[e]; mys[i] = srcs[e];
            atomicAdd(&lh[myd[i] >> 7], 1);
        } else myd[i] = -1;
    }
    __syncthreads();
    for (int i = threadIdx.x; i < NBUCK; i += 256) {
        const int c = lh[i];
        lbase[i] = c ? atomicAdd(&ccur[i], c) : 0;
    }
    __syncthreads();
#pragma unroll
    for (int i = 0; i < 16; ++i) {
        if (myd[i] >= 0) {
            const int e = base + i * 256 + threadIdx.x;
            const int b = myd[i] >> 7;
            const int r = atomicAdd(&lrank[b], 1);
            tmp[lbase[b] + r] =
                make_uint2((unsigned)mys[i] | ((unsigned)myd[i] << 16),
                           (unsigned)e);
        }
    }
}

// one block per bucket: LDS counting sort over the 128 local dsts
__global__ __launch_bounds__(256, 1) void fsort_kernel(
    const uint2* __restrict__ tmp, const int* __restrict__ coff,
    unsigned* __restrict__ sd2, int* __restrict__ eid)
{
    __shared__ uint2 ebuf[4096];
    __shared__ int lh[128], lsc[128];
    const int b = blockIdx.x;
    const int lo = coff[b];
    const int cnt = coff[b + 1] - lo;
    if (threadIdx.x < 128) lh[threadIdx.x] = 0;
    __syncthreads();
    for (int i = threadIdx.x; i < cnt; i += 256) {
        const uint2 v = tmp[lo + i];
        ebuf[i] = v;
        atomicAdd(&lh[(int)(v.x >> 16) - b * 128], 1);
    }
    __syncthreads();
    if (threadIdx.x < 128) lsc[threadIdx.x] = lh[threadIdx.x];
    __syncthreads();
    for (int off = 1; off < 128; off <<= 1) {
        int v = 0;
        if (threadIdx.x < 128 && threadIdx.x >= off) v = lsc[threadIdx.x - off];
        __syncthreads();
        if (threadIdx.x < 128) lsc[threadIdx.x] += v;
        __syncthreads();
    }
    if (threadIdx.x < 128) lh[threadIdx.x] = lsc[threadIdx.x] - lh[threadIdx.x];
    __syncthreads();
    for (int i = threadIdx.x; i < cnt; i += 256) {
        const uint2 v = ebuf[i];
        const int d = (int)(v.x >> 16) - b * 128;
        const int pos = atomicAdd(&lh[d], 1);
        sd2[lo + pos] = v.x;
        eid[lo + pos] = (int)v.y;
    }
}

// ---------------------------------------------------------------------------
// h0 = x @ node_W + node_b      [N,128]@[128,64]; also fp16 copy for gathers
// ---------------------------------------------------------------------------
__global__ __launch_bounds__(256, 2) void node_proj_kernel(
    const float* __restrict__ x, const float* __restrict__ W,
    const float* __restrict__ b, float* __restrict__ h, __half* __restrict__ zh)
{
    __shared__ float xs[4][IN_DIM];
    const int c = threadIdx.x & 63;
    const int local_n = threadIdx.x >> 6;
    float w[IN_DIM];
#pragma unroll
    for (int k = 0; k < IN_DIM; ++k) w[k] = W[k * HID + c];
    const float bias = b[c];

    for (int base = blockIdx.x * 4; base < N_NODES; base += gridDim.x * 4) {
        __syncthreads();
#pragma unroll
        for (int i = 0; i < 2; ++i) {
            int idx = threadIdx.x + i * 256;
            int nn = idx >> 7, kk = idx & 127;
            xs[nn][kk] = x[(base + nn) * IN_DIM + kk];
        }
        __syncthreads();
        const int n = base + local_n;
        float acc = bias;
#pragma unroll
        for (int k4 = 0; k4 < IN_DIM / 4; ++k4) {
            float4 xv = ((const float4*)xs[local_n])[k4];
            acc = fmaf(xv.x, w[k4 * 4 + 0], acc);
            acc = fmaf(xv.y, w[k4 * 4 + 1], acc);
            acc = fmaf(xv.z, w[k4 * 4 + 2], acc);
            acc = fmaf(xv.w, w[k4 * 4 + 3], acc);
        }
        h[n * HID + c] = acc;
        zh[n * HID + c] = __float2half(acc);
    }
}

// ---------------------------------------------------------------------------
// edge embedding via MFMA (16 edges/wave, K padded 16->32), LDS transpose.
// Reads ea[eid[pos]] (random 64B full-line gathers), stores eah STREAMING.
// ---------------------------------------------------------------------------
__global__ __launch_bounds__(256, 4) void edge_emb_kernel(
    const float* __restrict__ ea, const float* __restrict__ W,
    const float* __restrict__ b, const int* __restrict__ eid,
    __half* __restrict__ eah)
{
    __shared__ __half lds_t[4][16 * HID];            // 2KB per wave
    const int lane = threadIdx.x & 63;
    const int waveid = threadIdx.x >> 6;
    const int wave = (blockIdx.x * 256 + threadIdx.x) >> 6;
    const int nwaves = gridDim.x * 4;
    const int m = lane & 15, q = lane >> 4;
    const int NT = N_EDGES / 16;                     // 50000

    half8 bf[4];
#pragma unroll
    for (int blk = 0; blk < 4; ++blk) {
#pragma unroll
        for (int i = 0; i < 8; ++i) {
            const int k = q * 8 + i;
            bf[blk][i] = (k < EDGE_DIM)
                ? (_Float16)W[k * HID + blk * 16 + m] : (_Float16)0.f;
        }
    }
    float bv[4];
#pragma unroll
    for (int blk = 0; blk < 4; ++blk) bv[blk] = b[blk * 16 + m];

    const int ed = lane >> 3, ch = lane & 7;         // store mapping

    for (int tile = wave; tile < NT; tile += nwaves) {
        const int e0 = tile * 16;
        const int eidx = eid[e0 + m];                // gather source row id
        half8 af;
#pragma unroll
        for (int i = 0; i < 8; ++i) af[i] = (_Float16)0.f;
        if (q < 2) {
            const float4* ap =
                (const float4*)(ea + (size_t)eidx * EDGE_DIM + q * 8);
            const float4 lo = ap[0];
            const float4 hi = ap[1];
            af[0] = (_Float16)lo.x; af[1] = (_Float16)lo.y;
            af[2] = (_Float16)lo.z; af[3] = (_Float16)lo.w;
            af[4] = (_Float16)hi.x; af[5] = (_Float16)hi.y;
            af[6] = (_Float16)hi.z; af[7] = (_Float16)hi.w;
        }
        floatx4 c[4];
#pragma unroll
        for (int blk = 0; blk < 4; ++blk) {
            floatx4 cin = {bv[blk], bv[blk], bv[blk], bv[blk]};
            c[blk] = __builtin_amdgcn_mfma_f32_16x16x32_f16(
                af, bf[blk], cin, 0, 0, 0);
        }
#pragma unroll
        for (int blk = 0; blk < 4; ++blk)
#pragma unroll
            for (int r = 0; r < 4; ++r)
                lds_t[waveid][(q * 4 + r) * HID + blk * 16 + m] =
                    __float2half(c[blk][r]);
        // streaming contiguous stores: 2x 16B per lane
        const float4 v0 =
            *(const float4*)&lds_t[waveid][ed * HID + ch * 8];
        const float4 v1 =
            *(const float4*)&lds_t[waveid][(8 + ed) * HID + ch * 8];
        ((float4*)(eah + (size_t)(e0 + ed) * HID))[ch] = v0;
        ((float4*)(eah + (size_t)(e0 + 8 + ed) * HID))[ch] = v1;
    }
}

// ---------------------------------------------------------------------------
// Edge-major segmented softmax-aggregate:
// ALL 64 eah streaming loads issued up-front (independent of sd2), zh
// gathers in 16-edge groups with depth-2 prefetch -> ~90 loads in flight.
// ---------------------------------------------------------------------------
__global__ __launch_bounds__(256, 3) void edge_agg_kernel(
    const __half* __restrict__ zh, const __half* __restrict__ eah,
    const unsigned* __restrict__ sd2,
    const float* __restrict__ conv_t, int layer,
    float* __restrict__ p, float* __restrict__ s)
{
    const int lane = threadIdx.x & 63;
    const int wave = (blockIdx.x * 256 + threadIdx.x) >> 6;
    const int nwaves = gridDim.x * 4;
    const float t2 = conv_t[layer] * 1.4426950408889634f;  // log2(e)*t
    const int NT = N_EDGES / 64;                     // 12500

    const _Float16* zf = (const _Float16*)zh;
    const _Float16* ef = (const _Float16*)eah;

    for (int tile = wave; tile < NT; tile += nwaves) {
        const int e0 = tile * 64;
        const unsigned sdv = sd2[e0 + lane];         // one coalesced 4B load
        const _Float16* erow = ef + (size_t)e0 * HID + lane;

        // issue ALL eah streaming loads up-front (no sd2 dependence)
        _Float16 ez[64];
#pragma unroll
        for (int k = 0; k < 64; ++k) ez[k] = erow[(size_t)k * HID];

        const int sv = (int)(sdv & 0xffffu);
        const int dv = (int)(sdv >> 16);
        const int pv = __shfl_up(dv, 1, 64);
        const unsigned long long bmask = __ballot(dv != pv) & ~1ull;

        _Float16 za[16], zb[16];
#pragma unroll
        for (int k = 0; k < 16; ++k) {               // prologue: group 0
            const int a = __builtin_amdgcn_readlane(sv, k);
            za[k] = zf[(size_t)a * HID + lane];
        }

        float S = 0.f, P = 0.f;
        int cur = __builtin_amdgcn_readlane(dv, 0);
#pragma unroll
        for (int g = 0; g < 4; ++g) {
            if (g < 3) {                             // prefetch group g+1
#pragma unroll
                for (int k = 0; k < 16; ++k) {
                    const int a = __builtin_amdgcn_readlane(sv, (g + 1) * 16 + k);
                    zb[k] = zf[(size_t)a * HID + lane];
                }
            }
#pragma unroll
            for (int k = 0; k < 16; ++k) {
                const int j = g * 16 + k;
                if (bmask & (1ull << j)) {           // SALU test, uniform
                    unsafeAtomicAdd(&s[(size_t)cur * HID + lane], S);
                    unsafeAtomicAdd(&p[(size_t)cur * HID + lane], P);
                    S = 0.f; P = 0.f;
                    cur = __builtin_amdgcn_readlane(dv, j);
                }
                _Float16 mh = za[k] + ez[j];
                mh = mh > (_Float16)0.f ? mh : (_Float16)0.f;
                const float mm = (float)mh + 1e-7f;
                const float xx = __builtin_amdgcn_exp2f(mm * t2);
                S += xx;
                P = fmaf(mm, xx, P);
            }
            if (g < 3) {
#pragma unroll
                for (int k = 0; k < 16; ++k) za[k] = zb[k];
            }
        }
        unsafeAtomicAdd(&s[(size_t)cur * HID + lane], S);
        unsafeAtomicAdd(&p[(size_t)cur * HID + lane], P);
    }
}

// ---------------------------------------------------------------------------
// mm1: one node per WAVE, barrier-free.
// lane j computes outputs j and j+64 of u = hin@W1 + b1, hin = p/s + zh.
// LN over 128 via in-wave butterfly (each lane holds 2 of the 128 outputs).
// Weights register-resident (128 VGPR/lane); hin broadcast via v_readlane.
// Also re-zeroes p,s for the next layer's aggregation.
// ---------------------------------------------------------------------------
__global__ __launch_bounds__(256, 3) void node_mm1_kernel(
    float* __restrict__ p, float* __restrict__ s,
    const __half* __restrict__ zh,
    const float* __restrict__ W1, const float* __restrict__ b1,
    const float* __restrict__ g1, const float* __restrict__ be1,
    __half* __restrict__ vh)
{
    const int lane = threadIdx.x & 63;
    const int wave = (blockIdx.x * 256 + threadIdx.x) >> 6;
    const int nwaves = gridDim.x * 4;

    float wa[HID], wb[HID];
#pragma unroll
    for (int k = 0; k < HID; ++k) {
        wa[k] = W1[k * HID2 + lane];
        wb[k] = W1[k * HID2 + 64 + lane];
    }
    const float ba = b1[lane],  bb = b1[64 + lane];
    const float ga = g1[lane],  gb = g1[64 + lane];
    const float ca = be1[lane], cb = be1[64 + lane];

    for (int n = wave; n < N_NODES; n += nwaves) {
        const int idx = n * HID + lane;
        const float pv = p[idx];
        const float sv = s[idx];
        const float zv = __half2float(zh[idx]);
        p[idx] = 0.f;                                // re-zero for next layer
        s[idx] = 0.f;
        const float hv = pv / (sv + 1e-16f) + zv;

        float a0 = 0.f, a1 = 0.f, c0 = 0.f, c1 = 0.f;  // 4 indep chains
#pragma unroll
        for (int k = 0; k < 32; ++k) {
            const float x0 = bcast(hv, k);
            const float x1 = bcast(hv, k + 32);
            a0 = fmaf(x0, wa[k], a0);
            c0 = fmaf(x0, wb[k], c0);
            a1 = fmaf(x1, wa[k + 32], a1);
            c1 = fmaf(x1, wb[k + 32], c1);
        }
        const float ua = (a0 + a1) + ba;
        const float ub = (c0 + c1) + bb;

        float sum = ua + ub;                         // LN over 128, in-wave
#pragma unroll
        for (int o = 1; o < 64; o <<= 1) sum += __shfl_xor(sum, o, 64);
        const float mu = sum * (1.f / 128.f);
        const float da = ua - mu, db = ub - mu;
        float q = fmaf(da, da, db * db);
#pragma unroll
        for (int o = 1; o < 64; o <<= 1) q += __shfl_xor(q, o, 64);
        const float rstd = rsqrtf(q * (1.f / 128.f) + 1e-5f);
        const float ya = da * rstd * ga + ca;
        const float yb = db * rstd * gb + cb;
        vh[(size_t)n * HID2 + lane]      = __float2half(ya > 0.f ? ya : 0.f);
        vh[(size_t)n * HID2 + 64 + lane] = __float2half(yb > 0.f ? yb : 0.f);
    }
}

// ---------------------------------------------------------------------------
// mm2: one node per WAVE, barrier-free.
// lane c computes out2[c] = vh[n]@W2[:,c] + b2[c]; h = (res? h:0)+out2;
// zh = fp16(relu(LN64(h)*gz+bz)) with in-wave butterfly LN.
// ---------------------------------------------------------------------------
__global__ __launch_bounds__(256, 3) void node_mm2_kernel(
    const __half* __restrict__ vh,
    const float* __restrict__ W2, const float* __restrict__ b2,
    const float* __restrict__ lng, const float* __restrict__ lnb,
    float* __restrict__ h, __half* __restrict__ zh, int residual)
{
    const int lane = threadIdx.x & 63;
    const int wave = (blockIdx.x * 256 + threadIdx.x) >> 6;
    const int nwaves = gridDim.x * 4;

    float wa[HID2 / 2], wb[HID2 / 2];   // wa[k]=W2[k][c], wb[k]=W2[k+64][c]
#pragma unroll
    for (int k = 0; k < HID2 / 2; ++k) {
        wa[k] = W2[k * HID + lane];
        wb[k] = W2[(k + 64) * HID + lane];
    }
    const float bias = b2[lane];
    const float g = lng[lane];
    const float be = lnb[lane];

    for (int n = wave; n < N_NODES; n += nwaves) {
        const float f0 = __half2float(vh[(size_t)n * HID2 + lane]);
        const float f1 = __half2float(vh[(size_t)n * HID2 + 64 + lane]);

        float a0 = 0.f, a1 = 0.f, c0 = 0.f, c1 = 0.f;  // 4 indep chains
#pragma unroll
        for (int k = 0; k < 32; ++k) {
            const float x0 = bcast(f0, k);
            const float x1 = bcast(f0, k + 32);
            const float x2 = bcast(f1, k);
            const float x3 = bcast(f1, k + 32);
            a0 = fmaf(x0, wa[k], a0);
            a1 = fmaf(x1, wa[k + 32], a1);
            c0 = fmaf(x2, wb[k], c0);
            c1 = fmaf(x3, wb[k + 32], c1);
        }
        const float acc = (a0 + a1) + (c0 + c1) + bias;

        const int idx = n * HID + lane;
        const float hn = residual ? (h[idx] + acc) : acc;
        h[idx] = hn;

        float sum = hn;                               // LN over 64, in-wave
#pragma unroll
        for (int o = 1; o < 64; o <<= 1) sum += __shfl_xor(sum, o, 64);
        const float mu = sum * (1.f / 64.f);
        const float d = hn - mu;
        float q = d * d;
#pragma unroll
        for (int o = 1; o < 64; o <<= 1) q += __shfl_xor(q, o, 64);
        const float var = q * (1.f / 64.f);
        const float y = d * rsqrtf(var + 1e-5f) * g + be;
        zh[idx] = __float2half(y > 0.f ? y : 0.f);
    }
}

// ---------------------------------------------------------------------------
// out = zh @ lin_W + lin_b      [N,64]@[64,8]
// ---------------------------------------------------------------------------
__global__ __launch_bounds__(256, 4) void final_kernel(
    const __half* __restrict__ zh, const float* __restrict__ Wl,
    const float* __restrict__ bl, float* __restrict__ out)
{
    __shared__ float wl[HID * OUT_DIM];
    for (int i = threadIdx.x; i < HID * OUT_DIM; i += 256) wl[i] = Wl[i];
    __syncthreads();
    const int total = N_NODES * OUT_DIM;
    for (int idx = blockIdx.x * 256 + threadIdx.x; idx < total;
         idx += gridDim.x * 256) {
        const int n = idx >> 3, o = idx & 7;
        const __half2* zp = (const __half2*)(zh + (size_t)n * HID);
        float acc = bl[o];
#pragma unroll
        for (int k2 = 0; k2 < HID / 2; ++k2) {
            const float2 f = __half22float2(zp[k2]);
            acc = fmaf(f.x, wl[(k2 * 2 + 0) * OUT_DIM + o], acc);
            acc = fmaf(f.y, wl[(k2 * 2 + 1) * OUT_DIM + o], acc);
        }
        out[idx] = acc;
    }
}

// ---------------------------------------------------------------------------
extern "C" void kernel_launch(void* const* d_in, const int* in_sizes, int n_in,
                              void* d_out, int out_size, void* d_ws, size_t ws_size,
                              hipStream_t stream)
{
    const float* x         = (const float*)d_in[0];
    const float* edge_attr = (const float*)d_in[1];
    const float* node_W    = (const float*)d_in[2];
    const float* node_b    = (const float*)d_in[3];
    const float* edge_W    = (const float*)d_in[4];
    const float* edge_b    = (const float*)d_in[5];
    const float* conv_t    = (const float*)d_in[6];
    const float* conv_W1   = (const float*)d_in[7];
    const float* conv_b1   = (const float*)d_in[8];
    const float* conv_g1   = (const float*)d_in[9];
    const float* conv_be1  = (const float*)d_in[10];
    const float* conv_W2   = (const float*)d_in[11];
    const float* conv_b2   = (const float*)d_in[12];
    const float* ln_g      = (const float*)d_in[13];
    const float* ln_b      = (const float*)d_in[14];
    const float* lin_W     = (const float*)d_in[15];
    const float* lin_b     = (const float*)d_in[16];
    const int*   edge_index= (const int*)d_in[17];
    const int*   srcs = edge_index;
    const int*   dsts = edge_index + N_EDGES;
    float* out = (float*)d_out;

    // workspace layout (~173 MB)
    float* h   = (float*)d_ws;                    // N*64
    float* p   = h   + N_NODES * HID;             // N*64
    float* s   = p   + N_NODES * HID;             // N*64 (contiguous w/ p)
    __half* vh  = (__half*)(s + N_NODES * HID);   // N*128 half
    __half* zh  = vh + (size_t)N_NODES * HID2;    // N*64 half
    __half* eah = zh + (size_t)N_NODES * HID;     // E*64 half
    uint2* tmp  = (uint2*)(eah + (size_t)N_EDGES * HID); // E x 8B
    unsigned* sd2 = (unsigned*)(tmp + N_EDGES);   // E x 4B
    int* eid    = (int*)(sd2 + N_EDGES);          // E x 4B
    int* ccnt   = eid + N_EDGES;                  // NBUCK
    int* coff   = ccnt + NBUCK;                   // NBUCK+1
    int* ccur   = coff + NBUCK + 1;               // NBUCK

    // ---- two-level counting sort of edges by dst ----
    hipMemsetAsync(ccnt, 0, (size_t)NBUCK * sizeof(int), stream);
    chist_kernel<<<CBLOCKS, 256, 0, stream>>>(dsts, ccnt);
    cscan_kernel<<<1, 256, 0, stream>>>(ccnt, coff, ccur);
    cscatter_kernel<<<CBLOCKS, 256, 0, stream>>>(srcs, dsts, ccur, tmp);
    fsort_kernel<<<NBUCK, 256, 0, stream>>>(tmp, coff, sd2, eid);

    node_proj_kernel<<<2048, 256, 0, stream>>>(x, node_W, node_b, h, zh);
    edge_emb_kernel<<<3125, 256, 0, stream>>>(edge_attr, edge_W, edge_b, eid, eah);

    // zero p,s once; node_mm1 re-zeroes them for the next layer
    hipMemsetAsync(p, 0, (size_t)2 * N_NODES * HID * sizeof(float), stream);

    for (int layer = 0; layer < N_LAYERS; ++layer) {
        edge_agg_kernel<<<3125, 256, 0, stream>>>(zh, eah, sd2,
                                                  conv_t, layer, p, s);
        node_mm1_kernel<<<2048, 256, 0, stream>>>(
            p, s, zh,
            conv_W1 + (size_t)layer * HID * HID2, conv_b1 + layer * HID2,
            conv_g1 + layer * HID2, conv_be1 + layer * HID2, vh);
        const float* gz = (layer < N_LAYERS - 1) ? (ln_g + (layer + 1) * HID) : ln_g;
        const float* bz = (layer < N_LAYERS - 1) ? (ln_b + (layer + 1) * HID) : ln_b;
        node_mm2_kernel<<<2048, 256, 0, stream>>>(
            vh, conv_W2 + (size_t)layer * HID2 * HID, conv_b2 + layer * HID,
            gz, bz, h, zh, layer > 0 ? 1 : 0);
    }
    final_kernel<<<1024, 256, 0, stream>>>(zh, lin_W, lin_b, out);
}